// Round 5
// baseline (42.898 us; speedup 1.0000x reference)
//
#include <hip/hip_runtime.h>

// VISIBILITY PROBE: R2's packed-Horner math, repeated REP=4 times inside the
// kernel with asm opacity (no CSE/DCE across reps) so the dispatch (~47us)
// outlasts the 40us harness fills and lands in rocprof's top-5 -> read
// VALUBusy/Occupancy/VGPR for OUR kernel. Output identical to R2 (last rep
// stores; all reps compute the same values).

typedef float v2f __attribute__((ext_vector_type(2)));

#define EPT 8
#define REP 4

__global__ __launch_bounds__(256) void rationals_kernel(
    const float* __restrict__ x,
    const float* __restrict__ coeff,
    float* __restrict__ out, int N) {
    int idx = (blockIdx.x * blockDim.x + threadIdx.x) * EPT;
    if (idx >= N) return;

    float xs[EPT];
    float4 xa = *reinterpret_cast<const float4*>(x + idx);
    float4 xb = *reinterpret_cast<const float4*>(x + idx + 4);
    xs[0] = xa.x; xs[1] = xa.y; xs[2] = xa.z; xs[3] = xa.w;
    xs[4] = xb.x; xs[5] = xb.y; xs[6] = xb.z; xs[7] = xb.w;

    float cn_top = coeff[63];
    float cd_top = coeff[127];

    float o[EPT];
    for (int r = 0; r < REP; ++r) {
        // Opacity: make xs "fresh" each rep so the Horner chain re-executes.
#pragma unroll
        for (int j = 0; j < EPT; ++j) asm volatile("" : "+v"(xs[j]));

        v2f xx[EPT], h[EPT];
#pragma unroll
        for (int j = 0; j < EPT; ++j) {
            xx[j] = (v2f){xs[j], xs[j]};
            h[j]  = (v2f){cn_top, cd_top};
        }

#pragma unroll
        for (int p = 62; p >= 0; --p) {
            v2f c2 = {coeff[p], coeff[64 + p]};
#pragma unroll
            for (int j = 0; j < EPT; ++j)
                h[j] = __builtin_elementwise_fma(h[j], xx[j], c2);
        }

#pragma unroll
        for (int j = 0; j < EPT; ++j) {
            float den = h[j].y * xs[j];
            o[j] = h[j].x * __builtin_amdgcn_rcpf(fabsf(den) + 1.0f);
            asm volatile("" :: "v"(o[j]));  // keep every rep's result live
        }
    }

    *reinterpret_cast<float4*>(out + idx)     = (float4){o[0], o[1], o[2], o[3]};
    *reinterpret_cast<float4*>(out + idx + 4) = (float4){o[4], o[5], o[6], o[7]};
}

extern "C" void kernel_launch(void* const* d_in, const int* in_sizes, int n_in,
                              void* d_out, int out_size, void* d_ws, size_t ws_size,
                              hipStream_t stream) {
    const float* x     = (const float*)d_in[0];
    const float* coeff = (const float*)d_in[1];
    float* out = (float*)d_out;
    int N = in_sizes[0];

    int threads = 256;
    int elems_per_block = threads * EPT;
    int blocks = (N + elems_per_block - 1) / elems_per_block;  // 2048
    rationals_kernel<<<blocks, threads, 0, stream>>>(x, coeff, out, N);
}

// Round 6
// 18.276 us; speedup vs baseline: 2.3472x; 2.3472x over previous
//
#include <hip/hip_runtime.h>

// out[i] = P(x[i]) / (|x[i]*Q(x[i])| + 1), packed Horner h={num,den}.
//
// R5 diagnosis: VGPR_Count=20 proved the pre-RA scheduler serialized the 8
// independent Horner chains (register-pressure heuristic), collapsing ILP ->
// dep-latency bound, VALUBusy 63%. Fix:
//  (1) asm volatile("") fence after every p-step: all 8 chains' step-p emit
//      before any step-(p+1) -> issue-bound groups of 8 independent pk_fma.
//  (2) preload all 63 coefficient pairs into VGPRs, pinned via asm("+v") so
//      the allocator cannot remat s_loads inside fenced regions (which would
//      insert per-step s_waitcnt(0) stalls -- the R4 failure mode).
// Budget: ~170 VGPR -> 3 waves/SIMD; per-wave ILP (8 chains) saturates issue.
// Floor: 504 pk_fma x 4cyc = 6.7us true + 5.3us harness overhead.

typedef float v2f __attribute__((ext_vector_type(2)));

#define EPT 8

__global__ __launch_bounds__(256) void rationals_kernel(
    const float* __restrict__ x,
    const float* __restrict__ coeff,
    float* __restrict__ out, int N) {
    int idx = (blockIdx.x * blockDim.x + threadIdx.x) * EPT;
    if (idx >= N) return;

    // --- coefficient preload (uniform), pinned to VGPRs ---
    v2f cc[63];
#pragma unroll
    for (int p = 0; p < 63; ++p)
        cc[p] = (v2f){coeff[p], coeff[64 + p]};
#pragma unroll
    for (int p = 0; p < 63; ++p)
        asm volatile("" : "+v"(cc[p]));

    float4 xa = *reinterpret_cast<const float4*>(x + idx);
    float4 xb = *reinterpret_cast<const float4*>(x + idx + 4);
    float xs[EPT] = {xa.x, xa.y, xa.z, xa.w, xb.x, xb.y, xb.z, xb.w};

    v2f xx[EPT], h[EPT];
    float cn_top = coeff[63];
    float cd_top = coeff[127];
#pragma unroll
    for (int j = 0; j < EPT; ++j) {
        xx[j] = (v2f){xs[j], xs[j]};
        h[j]  = (v2f){cn_top, cd_top};
    }

#pragma unroll
    for (int p = 62; p >= 0; --p) {
#pragma unroll
        for (int j = 0; j < EPT; ++j)
            h[j] = __builtin_elementwise_fma(h[j], xx[j], cc[p]);
        asm volatile("");  // scheduling fence: keep the 8 chains interleaved
    }

    float o[EPT];
#pragma unroll
    for (int j = 0; j < EPT; ++j) {
        float den = h[j].y * xx[j].x;
        o[j] = h[j].x * __builtin_amdgcn_rcpf(fabsf(den) + 1.0f);
    }
    *reinterpret_cast<float4*>(out + idx)     = (float4){o[0], o[1], o[2], o[3]};
    *reinterpret_cast<float4*>(out + idx + 4) = (float4){o[4], o[5], o[6], o[7]};
}

extern "C" void kernel_launch(void* const* d_in, const int* in_sizes, int n_in,
                              void* d_out, int out_size, void* d_ws, size_t ws_size,
                              hipStream_t stream) {
    const float* x     = (const float*)d_in[0];
    const float* coeff = (const float*)d_in[1];
    float* out = (float*)d_out;
    int N = in_sizes[0];  // 4194304, divisible by EPT

    int threads = 256;
    int elems_per_block = threads * EPT;
    int blocks = (N + elems_per_block - 1) / elems_per_block;  // 2048
    rationals_kernel<<<blocks, threads, 0, stream>>>(x, coeff, out, N);
}